// Round 12
// baseline (568.761 us; speedup 1.0000x reference)
//
#include <hip/hip_runtime.h>
#include <stdint.h>

#define NFFT    1024
#define HOP     160
#define NMELS   160
#define SEG     32000
#define PADW    512
#define XLEN    33024
#define NFRAMES 201
#define NBATCH  256
#define NFREQ   256              // bins 0..255 cover all nonzero mel weights
#define FBW     12
#define NSTEP   32               // K-steps of 32
#define ROWS    168              // padded samples per row (21 x uint4)
#define ROWB    336              // row bytes
#define CHB     4352             // uint4 chunks per batch in wp2 (= 17*256)
#define WPB     (CHB * 8)        // halfwords per batch in wp2 (34816)

using bf16x8 = __attribute__((ext_vector_type(8))) __bf16;
using f32x4  = __attribute__((ext_vector_type(4))) float;

static __device__ __forceinline__ uint16_t f2bf(float f) {
    union { float f; uint32_t u; } v; v.f = f;
    return (uint16_t)((v.u + 0x7FFFu + ((v.u >> 16) & 1u)) >> 16);
}
static __device__ __forceinline__ float bf2f(uint16_t h) {
    union { uint32_t u; float f; } v; v.u = (uint32_t)h << 16;
    return v.f;
}
static __device__ __forceinline__ void gload16(const void* g, void* l) {
    __builtin_amdgcn_global_load_lds(
        (const __attribute__((address_space(1))) uint32_t*)(uintptr_t)g,
        (__attribute__((address_space(3))) uint32_t*)(uintptr_t)l,
        16, 0, 0);
}

// ==== fused prep: pad(row-layout) | btf(frag-major) | fb ====
#define PAD_BLKS  4352            // 17 per batch x 256 batches
#define BTF_BLKS  256
#define PREP_GRID (PAD_BLKS + BTF_BLKS + 1)

__global__ void k_prep(const float* __restrict__ wav, const float* __restrict__ win,
                       const float* __restrict__ dre, const float* __restrict__ dimg,
                       const float* __restrict__ mfb,
                       uint16_t* __restrict__ wp2, uint16_t* __restrict__ BTf,
                       int* __restrict__ klo, int* __restrict__ kw,
                       float* __restrict__ fbv) {
    int bid = blockIdx.x, tid = threadIdx.x;
    if (bid < PAD_BLKS) {
        // reflect-pad waveform -> bf16 in 168-sample padded rows
        int b = bid / 17, ib = bid - b * 17;
        int chunk = ib * 256 + tid;          // 0..4351
        int row = chunk / 21, cc = chunk - row * 21;
        uint16_t r[8] = {0,0,0,0,0,0,0,0};
        if (cc < 20 && row < 207) {
            int s0 = row * 160 + cc * 8;     // padded-sample index (0-based at -512)
            if (s0 >= PADW && s0 + 8 <= PADW + SEG) {
                const float* s = wav + (size_t)b * SEG + (s0 - PADW);
                float4 v0 = *(const float4*)s;
                float4 v1 = *(const float4*)(s + 4);
                r[0]=f2bf(v0.x); r[1]=f2bf(v0.y); r[2]=f2bf(v0.z); r[3]=f2bf(v0.w);
                r[4]=f2bf(v1.x); r[5]=f2bf(v1.y); r[6]=f2bf(v1.z); r[7]=f2bf(v1.w);
            } else {
                #pragma unroll
                for (int e = 0; e < 8; ++e) {
                    int i = s0 + e - PADW;
                    int j = (i < 0) ? -i : ((i >= SEG) ? (2 * SEG - 2 - i) : i);
                    r[e] = f2bf(wav[(size_t)b * SEG + j]);
                }
            }
        }
        *(uint4*)(wp2 + (size_t)b * WPB + (size_t)chunk * 8) = *(const uint4*)r;
    } else if (bid < PAD_BLKS + BTF_BLKS) {
        // BTf fragment-major: flat ((vfrag*32 + kstep)*64 + lane)*8 halfwords,
        // vfrag = mat*16 + ntile; lane: l15 = bin%16, lg = k-chunk
        int idx8 = (bid - PAD_BLKS) * 256 + tid;
        int lane  = idx8 & 63;
        int kstep = (idx8 >> 6) & 31;
        int ntile = (idx8 >> 11) & 15;
        int mat   = idx8 >> 15;
        int bin = ntile * 16 + (lane & 15);
        int k0  = kstep * 32 + (lane >> 4) * 8;
        const float* src = (mat ? dimg : dre) + (size_t)bin * 1024 + k0;
        const float* w   = win + k0;
        uint16_t r[8];
        #pragma unroll
        for (int j = 0; j < 8; ++j) r[j] = f2bf(src[j] * w[j]);
        *(uint4*)(BTf + (size_t)idx8 * 8) = *(const uint4*)r;
    } else {
        int m = tid;
        if (m >= NMELS) return;
        int lo = -1, hi = -1;
        for (int f = 0; f < NFREQ; ++f) {
            float v = mfb[m * 513 + f];
            if (v > 0.f) { if (lo < 0) lo = f; hi = f; }
        }
        int w = (lo < 0) ? 0 : (hi - lo + 1);
        if (w > FBW) w = FBW;
        if (lo < 0) lo = 0;
        klo[m] = lo; kw[m] = w;
        for (int j = 0; j < w; ++j) fbv[m * FBW + j] = mfb[m * 513 + lo + j];
    }
}

// ==== main: ONE BLOCK PER BATCH (256 blocks = 1/CU), 16 waves, no K-loop barriers.
// A: whole batch waveform resident in LDS as 168-sample padded rows (214 rows,
//    71,904 B). Frame f, k-step t read at row f + t/5, col (32t%160) —
//    compile-time offsets under full unroll; 2-way bank aliasing only (free).
// B: frag-major BTf from global/L2, contiguous 1KB per wave-fragment.
// Waves: 2M x 8N. M: 13 frags (208 rows incl 7 garbage frames), split 7/7 with
// frag 6 duplicated (symmetric). N: wn*4+nf over 32 vfrags (256R + 256I bins).
// Epilogue: 4 x 64-row power slabs (bf16, stride 522) overlaid on waveform LDS.
// R12 fix: __launch_bounds__(1024, 1) — R11's (1024,4) capped unified regs at
// ~128 and spilled the 112-reg accumulator to scratch (1.75 GB scratch writes,
// 548us). With cap 512, ~200 unified regs fit; 1 block/CU as designed.
__global__ __launch_bounds__(1024, 1) void k_main(
    const uint16_t* __restrict__ wp2, const uint16_t* __restrict__ BTf,
    const int* __restrict__ klo, const int* __restrict__ kw,
    const float* __restrict__ fbv, float* __restrict__ out)
{
    __shared__ uint4 smem4[4494];            // 71,904 B
    char* smem = (char*)smem4;

    const int tid  = threadIdx.x;
    const int lane = tid & 63;
    const int wave = tid >> 6;               // 16 waves
    const int wm = wave >> 3, wn = wave & 7; // 2(M) x 8(N)
    const int l15 = lane & 15, lg = lane >> 4;
    const int b = blockIdx.x;

    // ---- fill LDS with this batch's padded waveform (linear copy, 4352 u4)
    const uint16_t* wsrc = wp2 + (size_t)b * WPB;
    {
        int idx = tid;
        #pragma unroll
        for (int r = 0; r < 4; ++r) {
            gload16(wsrc + (size_t)idx * 8, smem + (size_t)idx * 16);
            idx += 1024;
        }
        if (tid < 256)                       // wave-uniform (waves 0-3)
            gload16(wsrc + (size_t)idx * 8, smem + (size_t)idx * 16);
    }
    asm volatile("s_waitcnt vmcnt(0)" ::: "memory");
    __syncthreads();

    // ---- A-frag LDS byte bases (per M-frag), B global base
    const int g0 = wm ? 6 : 0;               // my first M-frag
    uint32_t abase[7];
    #pragma unroll
    for (int fi = 0; fi < 7; ++fi)
        abase[fi] = (uint32_t)(((g0 + fi) * 16 + l15) * ROWB + lg * 16);
    const uint16_t* bp = BTf + (size_t)wn * 65536 + lane * 8;

    f32x4 acc[7][4];
    #pragma unroll
    for (int fi = 0; fi < 7; ++fi)
        #pragma unroll
        for (int nf = 0; nf < 4; ++nf)
            acc[fi][nf] = f32x4{0.f, 0.f, 0.f, 0.f};

    // ---- K-loop: barrier-free, fully unrolled (A offsets fold to immediates)
    #pragma unroll
    for (int t = 0; t < NSTEP; ++t) {
        const int aoff = (t / 5) * ROWB + ((32 * t) % 160) * 2;
        bf16x8 bv[4];
        #pragma unroll
        for (int nf = 0; nf < 4; ++nf)
            bv[nf] = *(const bf16x8*)(bp + (size_t)nf * 16384 + (size_t)t * 512);
        bf16x8 av[7];
        #pragma unroll
        for (int fi = 0; fi < 7; ++fi)
            av[fi] = *(const bf16x8*)(smem + abase[fi] + aoff);
        __builtin_amdgcn_s_setprio(1);
        #pragma unroll
        for (int fi = 0; fi < 7; ++fi)
            #pragma unroll
            for (int nf = 0; nf < 4; ++nf)
                acc[fi][nf] = __builtin_amdgcn_mfma_f32_16x16x32_bf16(
                    av[fi], bv[nf], acc[fi][nf], 0, 0, 0);
        __builtin_amdgcn_s_setprio(0);
    }

    __syncthreads();                         // waveform dead; overlay power slabs

    // ---- epilogue: 4 slabs of 64 frames. pw[64][522] bf16: cols 0-255 = R^2,
    //      256-511 = I^2 (wn<4 writes R, wn>=4 writes I; no overlap).
    uint16_t* pw = (uint16_t*)smem;
    float* obase = out + (size_t)b * (NMELS * NFRAMES);
    #pragma unroll
    for (int s = 0; s < 4; ++s) {
        // power writes: frag g belongs to slab g>>2; wm1 skips dup frag 6
        #pragma unroll
        for (int fi = 0; fi < 7; ++fi) {
            const int g = g0 + fi;
            if (wm == 1 && fi == 0) continue;
            if ((g >> 2) != s) continue;
            #pragma unroll
            for (int nf = 0; nf < 4; ++nf) {
                const int vbin = (wn * 4 + nf) * 16 + l15;
                #pragma unroll
                for (int e = 0; e < 4; ++e) {
                    const int lr = (g & 3) * 16 + lg * 4 + e;
                    float v = acc[fi][nf][e];
                    pw[lr * 522 + vbin] = f2bf(v * v);
                }
            }
        }
        __syncthreads();
        // mel projection for this slab
        const int r0 = s * 64;
        const int nfr = (s < 3) ? 64 : (NFRAMES - 192);   // 64,64,64,9
        for (int task = tid; task < NMELS * 64; task += 1024) {
            int f = task & 63, m = task >> 6;
            if (f < nfr) {
                int lo = klo[m], w = kw[m];
                const uint16_t* pr = pw + f * 522 + lo;
                float a = 0.f;
                for (int j = 0; j < w; ++j)
                    a += fbv[m * FBW + j] * (bf2f(pr[j]) + bf2f(pr[256 + j]));
                obase[m * NFRAMES + r0 + f] = a;
            }
        }
        __syncthreads();
    }
}

extern "C" void kernel_launch(void* const* d_in, const int* in_sizes, int n_in,
                              void* d_out, int out_size, void* d_ws, size_t ws_size,
                              hipStream_t stream) {
    const float* wav  = (const float*)d_in[0];
    const float* win  = (const float*)d_in[1];
    const float* dre  = (const float*)d_in[2];
    const float* dimg = (const float*)d_in[3];
    const float* mfb  = (const float*)d_in[4];
    float* out = (float*)d_out;

    uint8_t* ws = (uint8_t*)d_ws;
    uint16_t* BTf = (uint16_t*)ws;                           // 1 MB frag-major DFT
    uint16_t* wp2 = (uint16_t*)(ws + (1u << 20));            // 17.8 MB row-padded wave
    size_t off = (1u << 20) + (size_t)NBATCH * WPB * 2;      // 18,875,392
    int*   klo = (int*)(ws + off);
    int*   kw  = (int*)(ws + off + 640);
    float* fbv = (float*)(ws + off + 1280);

    hipLaunchKernelGGL(k_prep, dim3(PREP_GRID), dim3(256), 0, stream,
                       wav, win, dre, dimg, mfb, wp2, BTf, klo, kw, fbv);
    hipLaunchKernelGGL(k_main, dim3(NBATCH), dim3(1024), 0, stream,
                       wp2, BTf, klo, kw, fbv, out);
}

// Round 13
// 120.613 us; speedup vs baseline: 4.7156x; 4.7156x over previous
//
#include <hip/hip_runtime.h>
#include <stdint.h>

#define NFFT    1024
#define HOP     160
#define NMELS   160
#define SEG     32000
#define PADW    512
#define XLEN    33024
#define NFRAMES 201
#define NBATCH  256
#define NFREQ   256              // bins 0..255 cover all nonzero mel weights
#define FBW     12
#define NSTEP   32               // K-steps of 32
#define ROWB    336              // padded row bytes (168 samples)
#define WPCH    4494             // u4 chunks per batch in wp2 (214 rows x 21)
#define WPB2    (WPCH * 8)       // halfwords per batch (35,952)
#define FILLCH  2496             // chunks filled per half (wave-aligned; >=2478)

using bf16x8 = __attribute__((ext_vector_type(8))) __bf16;
using f32x4  = __attribute__((ext_vector_type(4))) float;

static __device__ __forceinline__ uint16_t f2bf(float f) {
    union { float f; uint32_t u; } v; v.f = f;
    return (uint16_t)((v.u + 0x7FFFu + ((v.u >> 16) & 1u)) >> 16);
}
static __device__ __forceinline__ float bf2f(uint16_t h) {
    union { uint32_t u; float f; } v; v.u = (uint32_t)h << 16;
    return v.f;
}
static __device__ __forceinline__ void gload16(const void* g, void* l) {
    __builtin_amdgcn_global_load_lds(
        (const __attribute__((address_space(1))) uint32_t*)(uintptr_t)g,
        (__attribute__((address_space(3))) uint32_t*)(uintptr_t)l,
        16, 0, 0);
}

// ==== fused prep: pad(row-layout, 214 rows) | btf(frag-major) | fb ====
#define PAD_BLKS  (NBATCH * 18)   // 4608
#define BTF_BLKS  256
#define PREP_GRID (PAD_BLKS + BTF_BLKS + 1)

__global__ void k_prep(const float* __restrict__ wav, const float* __restrict__ win,
                       const float* __restrict__ dre, const float* __restrict__ dimg,
                       const float* __restrict__ mfb,
                       uint16_t* __restrict__ wp2, uint16_t* __restrict__ BTf,
                       int* __restrict__ klo, int* __restrict__ kw,
                       float* __restrict__ fbv) {
    int bid = blockIdx.x, tid = threadIdx.x;
    if (bid < PAD_BLKS) {
        int b = bid / 18, ib = bid - b * 18;
        int chunk = ib * 256 + tid;          // 0..4607
        if (chunk >= WPCH) return;
        int row = chunk / 21, cc = chunk - row * 21;
        uint16_t r[8] = {0,0,0,0,0,0,0,0};
        if (cc < 20) {
            int s0 = row * 160 + cc * 8;     // padded-sample index
            if (s0 >= PADW && s0 + 8 <= PADW + SEG) {
                const float* s = wav + (size_t)b * SEG + (s0 - PADW);
                float4 v0 = *(const float4*)s;
                float4 v1 = *(const float4*)(s + 4);
                r[0]=f2bf(v0.x); r[1]=f2bf(v0.y); r[2]=f2bf(v0.z); r[3]=f2bf(v0.w);
                r[4]=f2bf(v1.x); r[5]=f2bf(v1.y); r[6]=f2bf(v1.z); r[7]=f2bf(v1.w);
            } else {
                #pragma unroll
                for (int e = 0; e < 8; ++e) {
                    int i = s0 + e - PADW;   // reflect (stays in-bounds thru row 213)
                    int j = (i < 0) ? -i : ((i >= SEG) ? (2 * SEG - 2 - i) : i);
                    r[e] = f2bf(wav[(size_t)b * SEG + j]);
                }
            }
        }
        *(uint4*)(wp2 + (size_t)b * WPB2 + (size_t)chunk * 8) = *(const uint4*)r;
    } else if (bid < PAD_BLKS + BTF_BLKS) {
        // BTf frag-major: flat ((vfrag*32 + kstep)*64 + lane)*8 halfwords,
        // vfrag = mat*16 + ntile; lane: l15 = bin%16, lg = k-chunk
        int idx8 = (bid - PAD_BLKS) * 256 + tid;
        int lane  = idx8 & 63;
        int kstep = (idx8 >> 6) & 31;
        int ntile = (idx8 >> 11) & 15;
        int mat   = idx8 >> 15;
        int bin = ntile * 16 + (lane & 15);
        int k0  = kstep * 32 + (lane >> 4) * 8;
        const float* src = (mat ? dimg : dre) + (size_t)bin * 1024 + k0;
        const float* w   = win + k0;
        uint16_t r[8];
        #pragma unroll
        for (int j = 0; j < 8; ++j) r[j] = f2bf(src[j] * w[j]);
        *(uint4*)(BTf + (size_t)idx8 * 8) = *(const uint4*)r;
    } else {
        int m = tid;
        if (m >= NMELS) return;
        int lo = -1, hi = -1;
        for (int f = 0; f < NFREQ; ++f) {
            float v = mfb[m * 513 + f];
            if (v > 0.f) { if (lo < 0) lo = f; hi = f; }
        }
        int w = (lo < 0) ? 0 : (hi - lo + 1);
        if (w > FBW) w = FBW;
        if (lo < 0) lo = 0;
        klo[m] = lo; kw[m] = w;
        for (int j = 0; j < w; ++j) fbv[m * FBW + j] = mfb[m * 513 + lo + j];
    }
}

// ==== main: block = (batch, frame-half). 512 blocks = 2 clean rounds on 256 CUs.
// 8 waves (2/SIMD -> 256-reg cap), 1M x 8N: each wave owns ALL 7 M-frags
// (112 rows) x 4 vfrags (its 1/8 of 512 vbins). acc 112 + av 28 + bv 16 regs.
// A: half-waveform LDS-resident (118 rows x 336B = 39.6KB), barrier-free
//    fully-unrolled K-loop, ds_read_b128 at base + compile-time immediate.
// B: frag-major BTf, contiguous 1KB per wave-fragment from L2.
// Epilogue: 7 frag-slabs of 16 rows; bf16 power in LDS; masked direct stores
// (half0 owns frames 0..103, half1 owns 104..200). No atomics anywhere.
__global__ __launch_bounds__(512, 1) void k_main(
    const uint16_t* __restrict__ wp2, const uint16_t* __restrict__ BTf,
    const int* __restrict__ klo, const int* __restrict__ kw,
    const float* __restrict__ fbv, float* __restrict__ out)
{
    __shared__ uint4 smem4[FILLCH];          // 39,936 B
    char* smem = (char*)smem4;

    const int tid  = threadIdx.x;
    const int lane = tid & 63;
    const int wn   = tid >> 6;               // wave 0..7 = N-slice
    const int l15 = lane & 15, lg = lane >> 4;
    const int b    = blockIdx.x;
    const int half = blockIdx.y;
    const int r0   = half ? 96 : 0;          // first frame row of this half

    // ---- fill LDS with rows r0..r0+117 (+junk tail rows, never read as A)
    const uint16_t* wsrc = wp2 + (size_t)b * WPB2 + (size_t)r0 * 168;
    #pragma unroll
    for (int i = 0; i < 4; ++i)
        gload16(wsrc + (size_t)(tid + i * 512) * 8, smem + (size_t)(tid + i * 512) * 16);
    if (tid < FILLCH - 2048)                 // 448: wave-aligned
        gload16(wsrc + (size_t)(tid + 2048) * 8, smem + (size_t)(tid + 2048) * 16);
    asm volatile("s_waitcnt vmcnt(0)" ::: "memory");
    __syncthreads();

    // ---- A per-lane base (frag/k offsets are compile-time immediates)
    const uint32_t alane = (uint32_t)(l15 * ROWB + lg * 16);
    // ---- B base: wave's 4 vfrags start at wn*4; vfrag stride 16384 hw (32KB)
    const uint16_t* bp = BTf + (size_t)(wn * 4) * 16384 + lane * 8;

    f32x4 acc[7][4];
    #pragma unroll
    for (int fi = 0; fi < 7; ++fi)
        #pragma unroll
        for (int nf = 0; nf < 4; ++nf)
            acc[fi][nf] = f32x4{0.f, 0.f, 0.f, 0.f};

    // ---- K-loop: no barriers, fully unrolled
    #pragma unroll
    for (int t = 0; t < NSTEP; ++t) {
        const int aoff = (t / 5) * ROWB + ((32 * t) % 160) * 2;
        bf16x8 bv[4];
        #pragma unroll
        for (int nf = 0; nf < 4; ++nf)
            bv[nf] = *(const bf16x8*)(bp + (size_t)nf * 16384 + (size_t)t * 512);
        __builtin_amdgcn_s_setprio(1);
        #pragma unroll
        for (int fi = 0; fi < 7; ++fi) {
            bf16x8 av = *(const bf16x8*)(smem + alane + (uint32_t)(fi * 16 * ROWB + aoff));
            #pragma unroll
            for (int nf = 0; nf < 4; ++nf)
                acc[fi][nf] = __builtin_amdgcn_mfma_f32_16x16x32_bf16(
                    av, bv[nf], acc[fi][nf], 0, 0, 0);
        }
        __builtin_amdgcn_s_setprio(0);
    }
    __syncthreads();                         // waveform dead; overlay power slab

    // ---- epilogue: 7 slabs (one 16-row frag each). pw[16][522] bf16:
    //      cols 0..255 = R^2 (waves 0-3), 256..511 = I^2 (waves 4-7).
    uint16_t* pw = (uint16_t*)smem;
    float* obase = out + (size_t)b * (NMELS * NFRAMES);
    #pragma unroll
    for (int s = 0; s < 7; ++s) {
        #pragma unroll
        for (int nf = 0; nf < 4; ++nf) {
            const int col = wn * 64 + nf * 16 + l15;
            #pragma unroll
            for (int e = 0; e < 4; ++e) {
                float v = acc[s][nf][e];
                pw[(lg * 4 + e) * 522 + col] = f2bf(v * v);
            }
        }
        __syncthreads();
        // mel projection for frames fg = r0 + s*16 + fr
        for (int task = tid; task < NMELS * 16; task += 512) {
            int fr = task & 15, m = task >> 4;
            int fg = r0 + s * 16 + fr;
            bool own = half ? (fg >= 104 && fg <= 200) : (fg <= 103);
            if (own) {
                int lo = klo[m], w = kw[m];
                const uint16_t* pr = pw + fr * 522 + lo;
                float a = 0.f;
                for (int j = 0; j < w; ++j)
                    a += fbv[m * FBW + j] * (bf2f(pr[j]) + bf2f(pr[256 + j]));
                obase[m * NFRAMES + fg] = a;
            }
        }
        __syncthreads();
    }
}

extern "C" void kernel_launch(void* const* d_in, const int* in_sizes, int n_in,
                              void* d_out, int out_size, void* d_ws, size_t ws_size,
                              hipStream_t stream) {
    const float* wav  = (const float*)d_in[0];
    const float* win  = (const float*)d_in[1];
    const float* dre  = (const float*)d_in[2];
    const float* dimg = (const float*)d_in[3];
    const float* mfb  = (const float*)d_in[4];
    float* out = (float*)d_out;

    uint8_t* ws = (uint8_t*)d_ws;
    uint16_t* BTf = (uint16_t*)ws;                           // 1 MB frag-major DFT
    uint16_t* wp2 = (uint16_t*)(ws + (1u << 20));            // 18.4 MB row-padded wave
    size_t off = (1u << 20) + (size_t)NBATCH * WPB2 * 2;     // 19,456,000
    int*   klo = (int*)(ws + off);
    int*   kw  = (int*)(ws + off + 640);
    float* fbv = (float*)(ws + off + 1280);

    hipLaunchKernelGGL(k_prep, dim3(PREP_GRID), dim3(256), 0, stream,
                       wav, win, dre, dimg, mfb, wp2, BTf, klo, kw, fbv);
    hipLaunchKernelGGL(k_main, dim3(NBATCH, 2), dim3(512), 0, stream,
                       wp2, BTf, klo, kw, fbv, out);
}